// Round 15
// baseline (456.759 us; speedup 1.0000x reference)
//
#include <hip/hip_runtime.h>
#include <math.h>

#define N_NODES 50000
#define N_EDGES 800000
#define ND 128
#define ED 64
#define TD 16
#define OD 128
#define NH 4
#define INDIM 208   // ND+ED+TD
#define K2DIM 336   // INDIM + ND
#define KPAD 352    // K2DIM padded to 11*32
#define WTPITCH 360 // Wt row pitch in bf16 (bank-spread)
#define NPAD 50048  // nodes padded to 64

// workspace layout (float offsets). einfoC/efc are CSR-ORDERED (scattered by k1c).
// einfo layout (round-12): pk.x = s | dt16<<16 ; pk.y = bf16(ev0)|bf16(ev1)<<16 ;
//                          pk.z = bf16(ev2)|bf16(ev3)<<16 ; pk.w = 0
#define OFF_A      0ll           // 50048*352 ushort = 8,808,448 floats
#define OFF_EINFO  8808448ll     // 800000 uint4, CSR order
#define OFF_RANK   12008448ll    // 800000 ints (k_count: rank; k_pos overwrites with pos)
#define OFF_DENOM  12808448ll    // 16
#define OFF_SPG    12808464ll    // 16
#define OFF_WFUSE  12808480ll    // 832
#define OFF_BFUSE  12809312ll    // 16
#define OFF_BMO    12809328ll    // 128
#define OFF_XS4    12809456ll    // 200000
#define OFF_XD4    13009456ll    // 200000
#define OFF_CNT    13209456ll    // 50000 ints
#define OFF_START  13259456ll    // 50016 ints
#define OFF_SW     13309472ll    // 50048 floats
#define OFF_WT     13359520ll    // 128*360 ushort = 23040 floats
#define OFF_EFC    13382560ll    // 800000*64 ushort, CSR order = 25,600,000 floats
#define OFF_XBF    38982560ll    // 50000*128 ushort = 3,200,000 floats
#define WS_FLOATS  42182560ll

typedef __attribute__((ext_vector_type(8))) short short8v;
typedef __attribute__((ext_vector_type(4))) float f32x4;

__device__ inline unsigned short f2bf(float f) {
  unsigned u = __float_as_uint(f);
  unsigned r = (u + 0x7fffu + ((u >> 16) & 1u)) >> 16;
  return (unsigned short)r;
}
__device__ inline float bf2f(unsigned us) {
  return __uint_as_float(us << 16);
}

// ---------------- K0: fold weights + build bf16 Wt ----------------
__global__ void k0_prep(const float* __restrict__ Wm, const float* __restrict__ bm,
                        const float* __restrict__ Wa, const float* __restrict__ ba,
                        const float* __restrict__ Wo, const float* __restrict__ gammas,
                        float* __restrict__ ws) {
  int b = blockIdx.x, j = threadIdx.x;
  unsigned short* Wt = (unsigned short*)(ws + OFF_WT);
  if (b < INDIM) {
    float acc = 0.f;
    for (int m = 0; m < OD; ++m) acc += Wm[b * OD + m] * Wo[m * OD + j];
    Wt[j * WTPITCH + b] = f2bf(acc);
    if (j < NH) {
      float a = 0.f;
      for (int m = 0; m < OD; ++m) a += Wm[b * OD + m] * Wa[m * NH + j];
      ws[OFF_WFUSE + (long)b * NH + j] = a;
    }
  } else if (b < K2DIM) {
    Wt[j * WTPITCH + b] = f2bf(Wo[(OD + b - INDIM) * OD + j]);
  } else {
    if (j < TD) ws[OFF_SPG + j] = log1pf(expf(gammas[j]));
    if (j < NH) {
      float a = ba[j];
      for (int m = 0; m < OD; ++m) a += bm[m] * Wa[m * NH + j];
      ws[OFF_BFUSE + j] = a;
    }
    float a2 = 0.f;
    for (int m = 0; m < OD; ++m) a2 += bm[m] * Wo[m * OD + j];
    ws[OFF_BMO + j] = a2;
    for (int p = K2DIM; p < KPAD; ++p) Wt[j * WTPITCH + p] = 0;
  }
}

// ---------------- K0b: per-node 4-dim projections + x -> bf16 copy ----------------
__global__ __launch_bounds__(256) void k0b_nodeproj(
    const float* __restrict__ x, const float* __restrict__ Wa,
    float* __restrict__ ws) {
  __shared__ float wf[ND * NH];
  __shared__ float wab[ND * NH];
  int tid = threadIdx.x;
  for (int i = tid; i < ND * NH; i += 256) { wf[i] = ws[OFF_WFUSE + i]; wab[i] = Wa[ND * NH + i]; }
  __syncthreads();
  int lane = tid & 63, wv = tid >> 6;
  long n = (long)blockIdx.x * 4 + wv;
  if (n >= N_NODES) return;
  float v0 = x[n * ND + lane], v1 = x[n * ND + 64 + lane];
  unsigned short* xbf = (unsigned short*)(ws + OFF_XBF);
  xbf[n * ND + lane] = f2bf(v0);
  xbf[n * ND + 64 + lane] = f2bf(v1);
  float s0, s1, s2, s3, d0, d1, d2, d3;
  s0 = v0 * wf[lane * 4 + 0] + v1 * wf[(64 + lane) * 4 + 0];
  s1 = v0 * wf[lane * 4 + 1] + v1 * wf[(64 + lane) * 4 + 1];
  s2 = v0 * wf[lane * 4 + 2] + v1 * wf[(64 + lane) * 4 + 2];
  s3 = v0 * wf[lane * 4 + 3] + v1 * wf[(64 + lane) * 4 + 3];
  d0 = v0 * wab[lane * 4 + 0] + v1 * wab[(64 + lane) * 4 + 0];
  d1 = v0 * wab[lane * 4 + 1] + v1 * wab[(64 + lane) * 4 + 1];
  d2 = v0 * wab[lane * 4 + 2] + v1 * wab[(64 + lane) * 4 + 2];
  d3 = v0 * wab[lane * 4 + 3] + v1 * wab[(64 + lane) * 4 + 3];
  for (int off = 32; off; off >>= 1) {
    s0 += __shfl_xor(s0, off); s1 += __shfl_xor(s1, off);
    s2 += __shfl_xor(s2, off); s3 += __shfl_xor(s3, off);
    d0 += __shfl_xor(d0, off); d1 += __shfl_xor(d1, off);
    d2 += __shfl_xor(d2, off); d3 += __shfl_xor(d3, off);
  }
  if (lane == 0) {
    reinterpret_cast<float4*>(ws + OFF_XS4)[n] = make_float4(s0, s1, s2, s3);
    reinterpret_cast<float4*>(ws + OFF_XD4)[n] = make_float4(d0, d1, d2, d3);
  }
}

// ---------------- K_count: dst histogram + per-edge rank (atomic return value) ----------------
__global__ __launch_bounds__(256) void k_count(const int* __restrict__ ei,
                                               float* __restrict__ ws) {
  int* cnt = reinterpret_cast<int*>(ws + OFF_CNT);
  int* rank = reinterpret_cast<int*>(ws + OFF_RANK);
  for (long e = (long)blockIdx.x * 256 + threadIdx.x; e < N_EDGES;
       e += (long)gridDim.x * 256)
    rank[e] = atomicAdd(&cnt[ei[N_EDGES + e]], 1);
}

// ---------------- K_scan: exclusive scan (1024 threads) ----------------
__global__ __launch_bounds__(1024) void k_scan(float* __restrict__ ws) {
  const int* cnt = reinterpret_cast<const int*>(ws + OFF_CNT);
  int* startp = reinterpret_cast<int*>(ws + OFF_START);
  __shared__ int wsum[16];
  int tid = threadIdx.x;
  int lo = tid * 49, hi = min(lo + 49, N_NODES);
  int s = 0;
  for (int i = lo; i < hi; ++i) s += cnt[i];
  int lane = tid & 63, wv = tid >> 6;
  int sc = s;
  for (int off = 1; off < 64; off <<= 1) {
    int t = __shfl_up(sc, off);
    if (lane >= off) sc += t;
  }
  if (lane == 63) wsum[wv] = sc;
  __syncthreads();
  if (tid == 0) {
    int run = 0;
    for (int i = 0; i < 16; ++i) { int t = wsum[i]; wsum[i] = run; run += t; }
  }
  __syncthreads();
  int run = wsum[wv] + sc - s;   // exclusive prefix for this thread
  for (int i = lo; i < hi; ++i) { startp[i] = run; run += cnt[i]; }
  if (tid == 1023) startp[N_NODES] = run;
}

// ---------------- K_pos: pos[e] = start[dst[e]] + rank[e] (overwrites rank) ----------------
__global__ __launch_bounds__(256) void k_pos(const int* __restrict__ ei,
                                             float* __restrict__ ws) {
  const int* startp = reinterpret_cast<const int*>(ws + OFF_START);
  int* pr = reinterpret_cast<int*>(ws + OFF_RANK);
  for (long e = (long)blockIdx.x * 256 + threadIdx.x; e < N_EDGES;
       e += (long)gridDim.x * 256) {
    int d = ei[N_EDGES + e];
    pr[e] = startp[d] + pr[e];
  }
}

// ---------------- K1c: stream ef; scatter bf16 ef-row + einfo record into CSR slot ----------------
// 16 lanes per edge; 2-way unrolled grid-stride loop => two independent
// dependence chains per iteration (ILP latency hiding). Round-12 einfo layout.
__global__ __launch_bounds__(256) void k1c(
    const int* __restrict__ ei, const float* __restrict__ ef,
    const float* __restrict__ td, float* __restrict__ ws) {
  __shared__ float wef[ED * NH];
  __shared__ float wte[TD * NH];
  __shared__ float bf[NH];
  __shared__ float spg[TD];
  __shared__ float part[NH];
  int tid = threadIdx.x;
  for (int i = tid; i < ED * NH; i += 256) wef[i] = ws[OFF_WFUSE + ND * NH + i];
  if (tid < TD * NH) wte[tid] = ws[OFF_WFUSE + (ND + ED) * NH + tid];
  if (tid < NH) { bf[tid] = ws[OFF_BFUSE + tid]; part[tid] = 0.f; }
  if (tid < TD) spg[tid] = ws[OFF_SPG + tid];
  __syncthreads();

  int lane = tid & 63;
  int q = lane >> 4, r = lane & 15, h = r & 3;
  long wid = ((long)blockIdx.x * 256 + tid) >> 6;
  long stride = (long)gridDim.x * 16;
  const float4* ef4 = reinterpret_cast<const float4*>(ef);
  const float* xsf = ws + OFF_XS4;
  const float* xdf = ws + OFF_XD4;
  const int* posArr = reinterpret_cast<const int*>(ws + OFF_RANK);
  uint2* efc2 = reinterpret_cast<uint2*>(ws + OFF_EFC);
  uint4* einfoC = reinterpret_cast<uint4*>(ws + OFF_EINFO);

  float wr[16];
#pragma unroll
  for (int i = 0; i < 16; ++i) wr[i] = wef[16 * r + i];
  float spg_r = spg[r];
  float wt0 = wte[r * 4 + 0], wt1 = wte[r * 4 + 1];
  float wt2 = wte[r * 4 + 2], wt3 = wte[r * 4 + 3];
  float bfh = bf[h];
  float p = 0.f;
  int base16 = lane & 48;

  for (long eA = wid * 4 + q; eA < N_EDGES; eA += 2 * stride) {
    long eB = eA + stride;
    bool hB = eB < N_EDGES;
    long eBs = hB ? eB : eA;
    // ---- independent loads for both chains up front ----
    int sA = ei[eA], dA = ei[N_EDGES + eA];
    int sB = ei[eBs], dB = ei[N_EDGES + eBs];
    float dtA = fmaxf(td[eA], 0.f);
    float dtB = fmaxf(td[eBs], 0.f);
    int posA = posArr[eA];
    int posB = posArr[eBs];
    float4 efvA = ef4[eA * 16 + r];
    float4 efvB = ef4[eBs * 16 + r];
    float lsA = xsf[4l * sA + h], ldA = xdf[4l * dA + h];
    float lsB = xsf[4l * sB + h], ldB = xdf[4l * dB + h];
    float teA = __expf(-spg_r * dtA);
    float teB = __expf(-spg_r * dtB);
    // ---- efc scatter ----
    uint2 ebA, ebB;
    ebA.x = (unsigned)f2bf(efvA.x) | ((unsigned)f2bf(efvA.y) << 16);
    ebA.y = (unsigned)f2bf(efvA.z) | ((unsigned)f2bf(efvA.w) << 16);
    efc2[(long)posA * 16 + r] = ebA;
    ebB.x = (unsigned)f2bf(efvB.x) | ((unsigned)f2bf(efvB.y) << 16);
    ebB.y = (unsigned)f2bf(efvB.z) | ((unsigned)f2bf(efvB.w) << 16);
    if (hB) efc2[(long)posB * 16 + r] = ebB;
    // ---- chain A FMAs ----
    float a0A = efvA.x * wr[0] + efvA.y * wr[4] + efvA.z * wr[8]  + efvA.w * wr[12] + teA * wt0;
    float a1A = efvA.x * wr[1] + efvA.y * wr[5] + efvA.z * wr[9]  + efvA.w * wr[13] + teA * wt1;
    float a2A = efvA.x * wr[2] + efvA.y * wr[6] + efvA.z * wr[10] + efvA.w * wr[14] + teA * wt2;
    float a3A = efvA.x * wr[3] + efvA.y * wr[7] + efvA.z * wr[11] + efvA.w * wr[15] + teA * wt3;
    // ---- chain B FMAs ----
    float a0B = efvB.x * wr[0] + efvB.y * wr[4] + efvB.z * wr[8]  + efvB.w * wr[12] + teB * wt0;
    float a1B = efvB.x * wr[1] + efvB.y * wr[5] + efvB.z * wr[9]  + efvB.w * wr[13] + teB * wt1;
    float a2B = efvB.x * wr[2] + efvB.y * wr[6] + efvB.z * wr[10] + efvB.w * wr[14] + teB * wt2;
    float a3B = efvB.x * wr[3] + efvB.y * wr[7] + efvB.z * wr[11] + efvB.w * wr[15] + teB * wt3;
    // ---- interleaved reduces (independent chains hide shuffle latency) ----
    a0A += __shfl_xor(a0A, 1); a1A += __shfl_xor(a1A, 1);
    a2A += __shfl_xor(a2A, 1); a3A += __shfl_xor(a3A, 1);
    a0B += __shfl_xor(a0B, 1); a1B += __shfl_xor(a1B, 1);
    a2B += __shfl_xor(a2B, 1); a3B += __shfl_xor(a3B, 1);
    a0A += __shfl_xor(a0A, 2); a1A += __shfl_xor(a1A, 2);
    a2A += __shfl_xor(a2A, 2); a3A += __shfl_xor(a3A, 2);
    a0B += __shfl_xor(a0B, 2); a1B += __shfl_xor(a1B, 2);
    a2B += __shfl_xor(a2B, 2); a3B += __shfl_xor(a3B, 2);
    float vA = a0A;
    vA = (h == 1) ? a1A : vA;
    vA = (h == 2) ? a2A : vA;
    vA = (h == 3) ? a3A : vA;
    float vB = a0B;
    vB = (h == 1) ? a1B : vB;
    vB = (h == 2) ? a2B : vB;
    vB = (h == 3) ? a3B : vB;
    vA += __shfl_xor(vA, 4);
    vB += __shfl_xor(vB, 4);
    vA += __shfl_xor(vA, 8);
    vB += __shfl_xor(vB, 8);
    float evA = __expf(vA + lsA + ldA + bfh);
    float evB = __expf(vB + lsB + ldB + bfh);
    if (r < 4) {
      p += evA;
      if (hB) p += evB;
    }
    float e0A = __shfl(evA, base16 + 0), e1A = __shfl(evA, base16 + 1);
    float e2A = __shfl(evA, base16 + 2), e3A = __shfl(evA, base16 + 3);
    float e0B = __shfl(evB, base16 + 0), e1B = __shfl(evB, base16 + 1);
    float e2B = __shfl(evB, base16 + 2), e3B = __shfl(evB, base16 + 3);
    if (r == 0) {
      unsigned dt16A = (unsigned)(dtA * 65535.f + 0.5f);
      if (dt16A > 65535u) dt16A = 65535u;
      uint4 pkA;
      pkA.x = (unsigned)sA | (dt16A << 16);
      pkA.y = (unsigned)f2bf(e0A) | ((unsigned)f2bf(e1A) << 16);
      pkA.z = (unsigned)f2bf(e2A) | ((unsigned)f2bf(e3A) << 16);
      pkA.w = 0u;
      einfoC[posA] = pkA;
      if (hB) {
        unsigned dt16B = (unsigned)(dtB * 65535.f + 0.5f);
        if (dt16B > 65535u) dt16B = 65535u;
        uint4 pkB;
        pkB.x = (unsigned)sB | (dt16B << 16);
        pkB.y = (unsigned)f2bf(e0B) | ((unsigned)f2bf(e1B) << 16);
        pkB.z = (unsigned)f2bf(e2B) | ((unsigned)f2bf(e3B) << 16);
        pkB.w = 0u;
        einfoC[posB] = pkB;
      }
    }
  }
  p += __shfl_xor(p, 16);
  p += __shfl_xor(p, 32);
  if (lane < 4) atomicAdd(&part[lane], p);
  __syncthreads();
  if (tid < NH) atomicAdd(&ws[OFF_DENOM + tid], part[tid]);
}

// ---------------- K4a: CSR aggregation — STREAMING einfoC/efc (round-12 reader) ----------------
__global__ __launch_bounds__(256) void k4a_agg(float* __restrict__ ws) {
  __shared__ float spg_s[TD];
  __shared__ float invs[NH];
  int tid = threadIdx.x;
  if (tid < TD) spg_s[tid] = ws[OFF_SPG + tid];
  if (tid < NH) invs[tid] = 0.25f / ws[OFF_DENOM + tid];
  __syncthreads();
  int lane = tid & 63;
  long wid = (long)blockIdx.x * 4 + (tid >> 6);
  long nw = (long)gridDim.x * 4;
  const int* start = reinterpret_cast<const int*>(ws + OFF_START);
  const uint4* einfoC = reinterpret_cast<const uint4*>(ws + OFF_EINFO);
  unsigned short* A = (unsigned short*)(ws + OFF_A);
  const unsigned short* xbf = (const unsigned short*)(ws + OFF_XBF);
  const unsigned short* efc = (const unsigned short*)(ws + OFF_EFC);
  float spg_l = spg_s[lane & 15];
  float inv0 = invs[0], inv1 = invs[1], inv2 = invs[2], inv3 = invs[3];

  for (long n = wid; n < N_NODES; n += nw) {
    int i0 = start[n], i1 = start[n + 1];
    float a0 = 0.f, a1 = 0.f, a2 = 0.f, a3 = 0.f, asw = 0.f;
    for (int base = i0; base < i1; base += 64) {
      int m = min(64, i1 - base);
      uint4 pk = make_uint4(0u, 0u, 0u, 0u);
      if (lane < m) pk = einfoC[base + lane];   // coalesced
      int j = 0;
      for (; j + 4 <= m; j += 4) {
        unsigned xu[4], zu[4], wu[4];
#pragma unroll
        for (int u = 0; u < 4; ++u) {
          xu[u] = (unsigned)__shfl((int)pk.x, j + u);
          zu[u] = (unsigned)__shfl((int)pk.y, j + u);
          wu[u] = (unsigned)__shfl((int)pk.z, j + u);
        }
        unsigned xa[4], xb[4], ec[4];
#pragma unroll
        for (int u = 0; u < 4; ++u) {
          int s = (int)(xu[u] & 0xffffu);
          xa[u] = xbf[(long)s * ND + lane];
          xb[u] = xbf[(long)s * ND + 64 + lane];
          ec[u] = efc[(long)(base + j + u) * ED + lane];   // streaming
        }
#pragma unroll
        for (int u = 0; u < 4; ++u) {
          float w = bf2f(zu[u] & 0xffffu) * inv0 + bf2f(zu[u] >> 16) * inv1 +
                    bf2f(wu[u] & 0xffffu) * inv2 + bf2f(wu[u] >> 16) * inv3;
          float dt = (float)(xu[u] >> 16) * (1.f / 65535.f);
          a0 += w * bf2f(xa[u]);
          a1 += w * bf2f(xb[u]);
          a2 += w * bf2f(ec[u]);
          a3 += w * __expf(-spg_l * dt);
          asw += w;
        }
      }
      for (; j < m; ++j) {
        unsigned xu = (unsigned)__shfl((int)pk.x, j);
        unsigned zu = (unsigned)__shfl((int)pk.y, j);
        unsigned wu = (unsigned)__shfl((int)pk.z, j);
        int s = (int)(xu & 0xffffu);
        float w = bf2f(zu & 0xffffu) * inv0 + bf2f(zu >> 16) * inv1 +
                  bf2f(wu & 0xffffu) * inv2 + bf2f(wu >> 16) * inv3;
        float dt = (float)(xu >> 16) * (1.f / 65535.f);
        a0 += w * bf2f(xbf[(long)s * ND + lane]);
        a1 += w * bf2f(xbf[(long)s * ND + 64 + lane]);
        a2 += w * bf2f(efc[(long)(base + j) * ED + lane]);
        a3 += w * __expf(-spg_l * dt);
        asw += w;
      }
    }
    unsigned short* Ar = A + n * KPAD;
    Ar[lane] = f2bf(a0);
    Ar[64 + lane] = f2bf(a1);
    Ar[128 + lane] = f2bf(a2);
    if (lane < TD) Ar[192 + lane] = f2bf(a3);
    Ar[INDIM + lane] = xbf[n * ND + lane];
    Ar[INDIM + 64 + lane] = xbf[n * ND + 64 + lane];
    if (lane < 16) Ar[K2DIM + lane] = 0;
    if (lane == 0) ws[OFF_SW + n] = asw;
  }
}

// ---------------- K4b: MFMA bf16 GEMM (NPAD x KPAD @ KPAD x 128) + GELU + LN ----------------
__global__ __launch_bounds__(256) void k4b_mlp(
    const float* __restrict__ bo, const float* __restrict__ lng,
    const float* __restrict__ lnb, const float* __restrict__ ws,
    float* __restrict__ out) {
  __shared__ unsigned short wt[128 * WTPITCH];  // 90 KB, transposed W, bank-spread pitch
  __shared__ float tbl[512];                    // bo | bmj | lng | lnb
  int tid = threadIdx.x;
  {
    const unsigned* wg = (const unsigned*)(ws + OFF_WT);
    unsigned* wl = (unsigned*)wt;
    for (int i = tid; i < 128 * WTPITCH / 2; i += 256) wl[i] = wg[i];
    if (tid < 128) {
      tbl[tid] = bo[tid];
      tbl[128 + tid] = ws[OFF_BMO + tid];
      tbl[256 + tid] = lng[tid];
      tbl[384 + tid] = lnb[tid];
    }
  }
  __syncthreads();

  int lane = tid & 63, wv = tid >> 6;
  int c0 = lane & 15, grp = lane >> 4;
  long n0 = (long)blockIdx.x * 64 + (long)wv * 16;
  const unsigned short* A = (const unsigned short*)(ws + OFF_A);
  const unsigned short* Arow = A + (n0 + c0) * KPAD;

  f32x4 acc[8];
#pragma unroll
  for (int t = 0; t < 8; ++t) acc[t] = (f32x4){0.f, 0.f, 0.f, 0.f};

#pragma unroll
  for (int kt = 0; kt < 11; ++kt) {
    short8v afrag = *reinterpret_cast<const short8v*>(Arow + kt * 32 + grp * 8);
#pragma unroll
    for (int t = 0; t < 8; ++t) {
      short8v bfrag = *reinterpret_cast<const short8v*>(&wt[(t * 16 + c0) * WTPITCH + kt * 32 + grp * 8]);
      acc[t] = __builtin_amdgcn_mfma_f32_16x16x32_bf16(afrag, bfrag, acc[t], 0, 0, 0);
    }
  }

  const float* swp = ws + OFF_SW;
  float res[4][8];
#pragma unroll
  for (int r = 0; r < 4; ++r) {
    long row = n0 + grp * 4 + r;
    float sw = swp[row];
    float s = 0.f, s2 = 0.f;
#pragma unroll
    for (int t = 0; t < 8; ++t) {
      int col = c0 + 16 * t;
      float a = acc[t][r] + tbl[col] + sw * tbl[128 + col];
      float h = 0.5f * a * (1.f + erff(a * 0.70710678118654752f));
      res[r][t] = h;
      s += h; s2 += h * h;
    }
    s += __shfl_xor(s, 1);  s2 += __shfl_xor(s2, 1);
    s += __shfl_xor(s, 2);  s2 += __shfl_xor(s2, 2);
    s += __shfl_xor(s, 4);  s2 += __shfl_xor(s2, 4);
    s += __shfl_xor(s, 8);  s2 += __shfl_xor(s2, 8);
    float mu = s * (1.f / 128.f);
    float var = s2 * (1.f / 128.f) - mu * mu;
    float rstd = rsqrtf(var + 1e-5f);
    if (row < N_NODES) {
      float* op = out + row * OD;
#pragma unroll
      for (int t = 0; t < 8; ++t) {
        int col = c0 + 16 * t;
        op[col] = (res[r][t] - mu) * rstd * tbl[256 + col] + tbl[384 + col];
      }
    }
  }
}

extern "C" void kernel_launch(void* const* d_in, const int* in_sizes, int n_in,
                              void* d_out, int out_size, void* d_ws, size_t ws_size,
                              hipStream_t stream) {
  const float* x   = (const float*)d_in[0];
  const int*   ei  = (const int*)d_in[1];
  const float* ef  = (const float*)d_in[2];
  const float* td  = (const float*)d_in[3];
  const float* gm  = (const float*)d_in[4];
  const float* Wm  = (const float*)d_in[5];
  const float* bm  = (const float*)d_in[6];
  const float* Wa  = (const float*)d_in[7];
  const float* ba  = (const float*)d_in[8];
  const float* Wo  = (const float*)d_in[9];
  const float* bo  = (const float*)d_in[10];
  const float* lng = (const float*)d_in[11];
  const float* lnb = (const float*)d_in[12];
  float* ws = (float*)d_ws;
  float* out = (float*)d_out;
  if (ws_size < (size_t)WS_FLOATS * 4) return;

  hipMemsetAsync(ws + OFF_CNT, 0, 50000 * 4, stream);
  hipMemsetAsync(ws + OFF_DENOM, 0, 64, stream);

  k0_prep<<<K2DIM + 1, 128, 0, stream>>>(Wm, bm, Wa, ba, Wo, gm, ws);
  k0b_nodeproj<<<12500, 256, 0, stream>>>(x, Wa, ws);
  k_count<<<2048, 256, 0, stream>>>(ei, ws);
  k_scan<<<1, 1024, 0, stream>>>(ws);
  k_pos<<<2048, 256, 0, stream>>>(ei, ws);
  k1c<<<3072, 256, 0, stream>>>(ei, ef, td, ws);
  k4a_agg<<<2048, 256, 0, stream>>>(ws);
  k4b_mlp<<<(NPAD / 64), 256, 0, stream>>>(bo, lng, lnb, ws, out);
}

// Round 16
// 425.772 us; speedup vs baseline: 1.0728x; 1.0728x over previous
//
#include <hip/hip_runtime.h>
#include <math.h>

#define N_NODES 50000
#define N_EDGES 800000
#define ND 128
#define ED 64
#define TD 16
#define OD 128
#define NH 4
#define INDIM 208   // ND+ED+TD
#define K2DIM 336   // INDIM + ND
#define KPAD 352    // K2DIM padded to 11*32
#define WTPITCH 360 // Wt row pitch in bf16 (bank-spread)
#define NPAD 50048  // nodes padded to 64

// workspace layout (float offsets). einfoC/efc are CSR-ORDERED (scattered by k1c).
// einfo layout: pk.x = s | dt16<<16 ; pk.y = bf16(ev0)|bf16(ev1)<<16 ;
//               pk.z = bf16(ev2)|bf16(ev3)<<16 ; pk.w = 0
#define OFF_A      0ll           // 50048*352 ushort = 8,808,448 floats
#define OFF_EINFO  8808448ll     // 800000 uint4, CSR order
#define OFF_RANK   12008448ll    // 800000 ints (k_count: rank; k_pos overwrites with pos)
#define OFF_DENOM  12808448ll    // 16
#define OFF_SPG    12808464ll    // 16
#define OFF_WFUSE  12808480ll    // 832
#define OFF_BFUSE  12809312ll    // 16
#define OFF_BMO    12809328ll    // 128
#define OFF_XS4    12809456ll    // 200000
#define OFF_XD4    13009456ll    // 200000
#define OFF_CNT    13209456ll    // 50000 ints
#define OFF_START  13259456ll    // 50016 ints
#define OFF_SW     13309472ll    // 50048 floats
#define OFF_WT     13359520ll    // 128*360 ushort = 23040 floats
#define OFF_EFC    13382560ll    // 800000*64 ushort, CSR order = 25,600,000 floats
#define OFF_XBF    38982560ll    // 50000*128 ushort = 3,200,000 floats
#define WS_FLOATS  42182560ll

typedef __attribute__((ext_vector_type(8))) short short8v;
typedef __attribute__((ext_vector_type(4))) float f32x4;

__device__ inline unsigned short f2bf(float f) {
  unsigned u = __float_as_uint(f);
  unsigned r = (u + 0x7fffu + ((u >> 16) & 1u)) >> 16;
  return (unsigned short)r;
}
__device__ inline float bf2f(unsigned us) {
  return __uint_as_float(us << 16);
}

// ---------------- K0: fold weights + build bf16 Wt ----------------
__global__ void k0_prep(const float* __restrict__ Wm, const float* __restrict__ bm,
                        const float* __restrict__ Wa, const float* __restrict__ ba,
                        const float* __restrict__ Wo, const float* __restrict__ gammas,
                        float* __restrict__ ws) {
  int b = blockIdx.x, j = threadIdx.x;
  unsigned short* Wt = (unsigned short*)(ws + OFF_WT);
  if (b < INDIM) {
    float acc = 0.f;
    for (int m = 0; m < OD; ++m) acc += Wm[b * OD + m] * Wo[m * OD + j];
    Wt[j * WTPITCH + b] = f2bf(acc);
    if (j < NH) {
      float a = 0.f;
      for (int m = 0; m < OD; ++m) a += Wm[b * OD + m] * Wa[m * NH + j];
      ws[OFF_WFUSE + (long)b * NH + j] = a;
    }
  } else if (b < K2DIM) {
    Wt[j * WTPITCH + b] = f2bf(Wo[(OD + b - INDIM) * OD + j]);
  } else {
    if (j < TD) ws[OFF_SPG + j] = log1pf(expf(gammas[j]));
    if (j < NH) {
      float a = ba[j];
      for (int m = 0; m < OD; ++m) a += bm[m] * Wa[m * NH + j];
      ws[OFF_BFUSE + j] = a;
    }
    float a2 = 0.f;
    for (int m = 0; m < OD; ++m) a2 += bm[m] * Wo[m * OD + j];
    ws[OFF_BMO + j] = a2;
    for (int p = K2DIM; p < KPAD; ++p) Wt[j * WTPITCH + p] = 0;
  }
}

// ---------------- K0b: per-node 4-dim projections + x -> bf16 copy ----------------
__global__ __launch_bounds__(256) void k0b_nodeproj(
    const float* __restrict__ x, const float* __restrict__ Wa,
    float* __restrict__ ws) {
  __shared__ float wf[ND * NH];
  __shared__ float wab[ND * NH];
  int tid = threadIdx.x;
  for (int i = tid; i < ND * NH; i += 256) { wf[i] = ws[OFF_WFUSE + i]; wab[i] = Wa[ND * NH + i]; }
  __syncthreads();
  int lane = tid & 63, wv = tid >> 6;
  long n = (long)blockIdx.x * 4 + wv;
  if (n >= N_NODES) return;
  float v0 = x[n * ND + lane], v1 = x[n * ND + 64 + lane];
  unsigned short* xbf = (unsigned short*)(ws + OFF_XBF);
  xbf[n * ND + lane] = f2bf(v0);
  xbf[n * ND + 64 + lane] = f2bf(v1);
  float s0, s1, s2, s3, d0, d1, d2, d3;
  s0 = v0 * wf[lane * 4 + 0] + v1 * wf[(64 + lane) * 4 + 0];
  s1 = v0 * wf[lane * 4 + 1] + v1 * wf[(64 + lane) * 4 + 1];
  s2 = v0 * wf[lane * 4 + 2] + v1 * wf[(64 + lane) * 4 + 2];
  s3 = v0 * wf[lane * 4 + 3] + v1 * wf[(64 + lane) * 4 + 3];
  d0 = v0 * wab[lane * 4 + 0] + v1 * wab[(64 + lane) * 4 + 0];
  d1 = v0 * wab[lane * 4 + 1] + v1 * wab[(64 + lane) * 4 + 1];
  d2 = v0 * wab[lane * 4 + 2] + v1 * wab[(64 + lane) * 4 + 2];
  d3 = v0 * wab[lane * 4 + 3] + v1 * wab[(64 + lane) * 4 + 3];
  for (int off = 32; off; off >>= 1) {
    s0 += __shfl_xor(s0, off); s1 += __shfl_xor(s1, off);
    s2 += __shfl_xor(s2, off); s3 += __shfl_xor(s3, off);
    d0 += __shfl_xor(d0, off); d1 += __shfl_xor(d1, off);
    d2 += __shfl_xor(d2, off); d3 += __shfl_xor(d3, off);
  }
  if (lane == 0) {
    reinterpret_cast<float4*>(ws + OFF_XS4)[n] = make_float4(s0, s1, s2, s3);
    reinterpret_cast<float4*>(ws + OFF_XD4)[n] = make_float4(d0, d1, d2, d3);
  }
}

// ---------------- K_count: dst histogram + per-edge rank (atomic return value) ----------------
__global__ __launch_bounds__(256) void k_count(const int* __restrict__ ei,
                                               float* __restrict__ ws) {
  int* cnt = reinterpret_cast<int*>(ws + OFF_CNT);
  int* rank = reinterpret_cast<int*>(ws + OFF_RANK);
  for (long e = (long)blockIdx.x * 256 + threadIdx.x; e < N_EDGES;
       e += (long)gridDim.x * 256)
    rank[e] = atomicAdd(&cnt[ei[N_EDGES + e]], 1);
}

// ---------------- K_scan: exclusive scan (1024 threads) ----------------
__global__ __launch_bounds__(1024) void k_scan(float* __restrict__ ws) {
  const int* cnt = reinterpret_cast<const int*>(ws + OFF_CNT);
  int* startp = reinterpret_cast<int*>(ws + OFF_START);
  __shared__ int wsum[16];
  int tid = threadIdx.x;
  int lo = tid * 49, hi = min(lo + 49, N_NODES);
  int s = 0;
  for (int i = lo; i < hi; ++i) s += cnt[i];
  int lane = tid & 63, wv = tid >> 6;
  int sc = s;
  for (int off = 1; off < 64; off <<= 1) {
    int t = __shfl_up(sc, off);
    if (lane >= off) sc += t;
  }
  if (lane == 63) wsum[wv] = sc;
  __syncthreads();
  if (tid == 0) {
    int run = 0;
    for (int i = 0; i < 16; ++i) { int t = wsum[i]; wsum[i] = run; run += t; }
  }
  __syncthreads();
  int run = wsum[wv] + sc - s;   // exclusive prefix for this thread
  for (int i = lo; i < hi; ++i) { startp[i] = run; run += cnt[i]; }
  if (tid == 1023) startp[N_NODES] = run;
}

// ---------------- K_pos: pos[e] = start[dst[e]] + rank[e] (overwrites rank) ----------------
__global__ __launch_bounds__(256) void k_pos(const int* __restrict__ ei,
                                             float* __restrict__ ws) {
  const int* startp = reinterpret_cast<const int*>(ws + OFF_START);
  int* pr = reinterpret_cast<int*>(ws + OFF_RANK);
  for (long e = (long)blockIdx.x * 256 + threadIdx.x; e < N_EDGES;
       e += (long)gridDim.x * 256) {
    int d = ei[N_EDGES + e];
    pr[e] = startp[d] + pr[e];
  }
}

// ---------------- K1c: stream ef; scatter bf16 ef-row + einfo record into CSR slot ----------------
// 16 lanes per edge (round-12 proven form). pos precomputed by k_pos -- NO atomics.
__global__ __launch_bounds__(256) void k1c(
    const int* __restrict__ ei, const float* __restrict__ ef,
    const float* __restrict__ td, float* __restrict__ ws) {
  __shared__ float wef[ED * NH];
  __shared__ float wte[TD * NH];
  __shared__ float bf[NH];
  __shared__ float spg[TD];
  __shared__ float part[NH];
  int tid = threadIdx.x;
  for (int i = tid; i < ED * NH; i += 256) wef[i] = ws[OFF_WFUSE + ND * NH + i];
  if (tid < TD * NH) wte[tid] = ws[OFF_WFUSE + (ND + ED) * NH + tid];
  if (tid < NH) { bf[tid] = ws[OFF_BFUSE + tid]; part[tid] = 0.f; }
  if (tid < TD) spg[tid] = ws[OFF_SPG + tid];
  __syncthreads();

  int lane = tid & 63;
  int q = lane >> 4, r = lane & 15, h = r & 3;
  long wid = ((long)blockIdx.x * 256 + tid) >> 6;
  long stride = (long)gridDim.x * 16;
  const float4* ef4 = reinterpret_cast<const float4*>(ef);
  const float* xsf = ws + OFF_XS4;
  const float* xdf = ws + OFF_XD4;
  const int* posArr = reinterpret_cast<const int*>(ws + OFF_RANK);
  uint2* efc2 = reinterpret_cast<uint2*>(ws + OFF_EFC);
  uint4* einfoC = reinterpret_cast<uint4*>(ws + OFF_EINFO);

  float wr[16];
#pragma unroll
  for (int i = 0; i < 16; ++i) wr[i] = wef[16 * r + i];
  float spg_r = spg[r];
  float wt0 = wte[r * 4 + 0], wt1 = wte[r * 4 + 1];
  float wt2 = wte[r * 4 + 2], wt3 = wte[r * 4 + 3];
  float bfh = bf[h];
  float p = 0.f;
  int base16 = lane & 48;

  for (long e = wid * 4 + q; e < N_EDGES; e += stride) {
    int s = ei[e];
    int d = ei[N_EDGES + e];
    float dt = fmaxf(td[e], 0.f);
    int pos = posArr[e];
    float4 efv = ef4[e * 16 + r];
    float ls = xsf[4l * s + h];
    float ld = xdf[4l * d + h];
    float te = __expf(-spg_r * dt);
    // bf16 ef row scattered to CSR slot (16 lanes -> one contiguous 128B line)
    uint2 eb;
    eb.x = (unsigned)f2bf(efv.x) | ((unsigned)f2bf(efv.y) << 16);
    eb.y = (unsigned)f2bf(efv.z) | ((unsigned)f2bf(efv.w) << 16);
    efc2[(long)pos * 16 + r] = eb;
    float a0 = efv.x * wr[0] + efv.y * wr[4] + efv.z * wr[8]  + efv.w * wr[12] + te * wt0;
    float a1 = efv.x * wr[1] + efv.y * wr[5] + efv.z * wr[9]  + efv.w * wr[13] + te * wt1;
    float a2 = efv.x * wr[2] + efv.y * wr[6] + efv.z * wr[10] + efv.w * wr[14] + te * wt2;
    float a3 = efv.x * wr[3] + efv.y * wr[7] + efv.z * wr[11] + efv.w * wr[15] + te * wt3;
    a0 += __shfl_xor(a0, 1); a1 += __shfl_xor(a1, 1);
    a2 += __shfl_xor(a2, 1); a3 += __shfl_xor(a3, 1);
    a0 += __shfl_xor(a0, 2); a1 += __shfl_xor(a1, 2);
    a2 += __shfl_xor(a2, 2); a3 += __shfl_xor(a3, 2);
    float v = a0;
    v = (h == 1) ? a1 : v;
    v = (h == 2) ? a2 : v;
    v = (h == 3) ? a3 : v;
    v += __shfl_xor(v, 4);
    v += __shfl_xor(v, 8);
    float ev = __expf(v + ls + ld + bfh);
    if (r < 4) p += ev;
    float e0 = __shfl(ev, base16 + 0), e1 = __shfl(ev, base16 + 1);
    float e2 = __shfl(ev, base16 + 2), e3 = __shfl(ev, base16 + 3);
    if (r == 0) {
      unsigned dt16 = (unsigned)(dt * 65535.f + 0.5f);
      if (dt16 > 65535u) dt16 = 65535u;
      uint4 pk;
      pk.x = (unsigned)s | (dt16 << 16);
      pk.y = (unsigned)f2bf(e0) | ((unsigned)f2bf(e1) << 16);
      pk.z = (unsigned)f2bf(e2) | ((unsigned)f2bf(e3) << 16);
      pk.w = 0u;
      einfoC[pos] = pk;
    }
  }
  p += __shfl_xor(p, 16);
  p += __shfl_xor(p, 32);
  if (lane < 4) atomicAdd(&part[lane], p);
  __syncthreads();
  if (tid < NH) atomicAdd(&ws[OFF_DENOM + tid], part[tid]);
}

// ---------------- K4a: CSR aggregation — STREAMING einfoC/efc, xbf gathers only ----------------
__global__ __launch_bounds__(256) void k4a_agg(float* __restrict__ ws) {
  __shared__ float spg_s[TD];
  __shared__ float invs[NH];
  int tid = threadIdx.x;
  if (tid < TD) spg_s[tid] = ws[OFF_SPG + tid];
  if (tid < NH) invs[tid] = 0.25f / ws[OFF_DENOM + tid];
  __syncthreads();
  int lane = tid & 63;
  long wid = (long)blockIdx.x * 4 + (tid >> 6);
  long nw = (long)gridDim.x * 4;
  const int* start = reinterpret_cast<const int*>(ws + OFF_START);
  const uint4* einfoC = reinterpret_cast<const uint4*>(ws + OFF_EINFO);
  unsigned short* A = (unsigned short*)(ws + OFF_A);
  const unsigned short* xbf = (const unsigned short*)(ws + OFF_XBF);
  const unsigned short* efc = (const unsigned short*)(ws + OFF_EFC);
  float spg_l = spg_s[lane & 15];
  float inv0 = invs[0], inv1 = invs[1], inv2 = invs[2], inv3 = invs[3];

  for (long n = wid; n < N_NODES; n += nw) {
    int i0 = start[n], i1 = start[n + 1];
    float a0 = 0.f, a1 = 0.f, a2 = 0.f, a3 = 0.f, asw = 0.f;
    for (int base = i0; base < i1; base += 64) {
      int m = min(64, i1 - base);
      uint4 pk = make_uint4(0u, 0u, 0u, 0u);
      if (lane < m) pk = einfoC[base + lane];   // coalesced
      int j = 0;
      for (; j + 4 <= m; j += 4) {
        unsigned xu[4], zu[4], wu[4];
#pragma unroll
        for (int u = 0; u < 4; ++u) {
          xu[u] = (unsigned)__shfl((int)pk.x, j + u);
          zu[u] = (unsigned)__shfl((int)pk.y, j + u);
          wu[u] = (unsigned)__shfl((int)pk.z, j + u);
        }
        unsigned xa[4], xb[4], ec[4];
#pragma unroll
        for (int u = 0; u < 4; ++u) {
          int s = (int)(xu[u] & 0xffffu);
          xa[u] = xbf[(long)s * ND + lane];
          xb[u] = xbf[(long)s * ND + 64 + lane];
          ec[u] = efc[(long)(base + j + u) * ED + lane];   // streaming
        }
#pragma unroll
        for (int u = 0; u < 4; ++u) {
          float w = bf2f(zu[u] & 0xffffu) * inv0 + bf2f(zu[u] >> 16) * inv1 +
                    bf2f(wu[u] & 0xffffu) * inv2 + bf2f(wu[u] >> 16) * inv3;
          float dt = (float)(xu[u] >> 16) * (1.f / 65535.f);
          a0 += w * bf2f(xa[u]);
          a1 += w * bf2f(xb[u]);
          a2 += w * bf2f(ec[u]);
          a3 += w * __expf(-spg_l * dt);
          asw += w;
        }
      }
      for (; j < m; ++j) {
        unsigned xu = (unsigned)__shfl((int)pk.x, j);
        unsigned zu = (unsigned)__shfl((int)pk.y, j);
        unsigned wu = (unsigned)__shfl((int)pk.z, j);
        int s = (int)(xu & 0xffffu);
        float w = bf2f(zu & 0xffffu) * inv0 + bf2f(zu >> 16) * inv1 +
                  bf2f(wu & 0xffffu) * inv2 + bf2f(wu >> 16) * inv3;
        float dt = (float)(xu >> 16) * (1.f / 65535.f);
        a0 += w * bf2f(xbf[(long)s * ND + lane]);
        a1 += w * bf2f(xbf[(long)s * ND + 64 + lane]);
        a2 += w * bf2f(efc[(long)(base + j) * ED + lane]);
        a3 += w * __expf(-spg_l * dt);
        asw += w;
      }
    }
    unsigned short* Ar = A + n * KPAD;
    Ar[lane] = f2bf(a0);
    Ar[64 + lane] = f2bf(a1);
    Ar[128 + lane] = f2bf(a2);
    if (lane < TD) Ar[192 + lane] = f2bf(a3);
    Ar[INDIM + lane] = xbf[n * ND + lane];
    Ar[INDIM + 64 + lane] = xbf[n * ND + 64 + lane];
    if (lane < 16) Ar[K2DIM + lane] = 0;
    if (lane == 0) ws[OFF_SW + n] = asw;
  }
}

// ---------------- K4b: MFMA bf16 GEMM (NPAD x KPAD @ KPAD x 128) + GELU + LN ----------------
__global__ __launch_bounds__(256) void k4b_mlp(
    const float* __restrict__ bo, const float* __restrict__ lng,
    const float* __restrict__ lnb, const float* __restrict__ ws,
    float* __restrict__ out) {
  __shared__ unsigned short wt[128 * WTPITCH];  // 90 KB, transposed W, bank-spread pitch
  __shared__ float tbl[512];                    // bo | bmj | lng | lnb
  int tid = threadIdx.x;
  {
    const unsigned* wg = (const unsigned*)(ws + OFF_WT);
    unsigned* wl = (unsigned*)wt;
    for (int i = tid; i < 128 * WTPITCH / 2; i += 256) wl[i] = wg[i];
    if (tid < 128) {
      tbl[tid] = bo[tid];
      tbl[128 + tid] = ws[OFF_BMO + tid];
      tbl[256 + tid] = lng[tid];
      tbl[384 + tid] = lnb[tid];
    }
  }
  __syncthreads();

  int lane = tid & 63, wv = tid >> 6;
  int c0 = lane & 15, grp = lane >> 4;
  long n0 = (long)blockIdx.x * 64 + (long)wv * 16;
  const unsigned short* A = (const unsigned short*)(ws + OFF_A);
  const unsigned short* Arow = A + (n0 + c0) * KPAD;

  f32x4 acc[8];
#pragma unroll
  for (int t = 0; t < 8; ++t) acc[t] = (f32x4){0.f, 0.f, 0.f, 0.f};

#pragma unroll
  for (int kt = 0; kt < 11; ++kt) {
    short8v afrag = *reinterpret_cast<const short8v*>(Arow + kt * 32 + grp * 8);
#pragma unroll
    for (int t = 0; t < 8; ++t) {
      short8v bfrag = *reinterpret_cast<const short8v*>(&wt[(t * 16 + c0) * WTPITCH + kt * 32 + grp * 8]);
      acc[t] = __builtin_amdgcn_mfma_f32_16x16x32_bf16(afrag, bfrag, acc[t], 0, 0, 0);
    }
  }

  const float* swp = ws + OFF_SW;
  float res[4][8];
#pragma unroll
  for (int r = 0; r < 4; ++r) {
    long row = n0 + grp * 4 + r;
    float sw = swp[row];
    float s = 0.f, s2 = 0.f;
#pragma unroll
    for (int t = 0; t < 8; ++t) {
      int col = c0 + 16 * t;
      float a = acc[t][r] + tbl[col] + sw * tbl[128 + col];
      float h = 0.5f * a * (1.f + erff(a * 0.70710678118654752f));
      res[r][t] = h;
      s += h; s2 += h * h;
    }
    s += __shfl_xor(s, 1);  s2 += __shfl_xor(s2, 1);
    s += __shfl_xor(s, 2);  s2 += __shfl_xor(s2, 2);
    s += __shfl_xor(s, 4);  s2 += __shfl_xor(s2, 4);
    s += __shfl_xor(s, 8);  s2 += __shfl_xor(s2, 8);
    float mu = s * (1.f / 128.f);
    float var = s2 * (1.f / 128.f) - mu * mu;
    float rstd = rsqrtf(var + 1e-5f);
    if (row < N_NODES) {
      float* op = out + row * OD;
#pragma unroll
      for (int t = 0; t < 8; ++t) {
        int col = c0 + 16 * t;
        op[col] = (res[r][t] - mu) * rstd * tbl[256 + col] + tbl[384 + col];
      }
    }
  }
}

extern "C" void kernel_launch(void* const* d_in, const int* in_sizes, int n_in,
                              void* d_out, int out_size, void* d_ws, size_t ws_size,
                              hipStream_t stream) {
  const float* x   = (const float*)d_in[0];
  const int*   ei  = (const int*)d_in[1];
  const float* ef  = (const float*)d_in[2];
  const float* td  = (const float*)d_in[3];
  const float* gm  = (const float*)d_in[4];
  const float* Wm  = (const float*)d_in[5];
  const float* bm  = (const float*)d_in[6];
  const float* Wa  = (const float*)d_in[7];
  const float* ba  = (const float*)d_in[8];
  const float* Wo  = (const float*)d_in[9];
  const float* bo  = (const float*)d_in[10];
  const float* lng = (const float*)d_in[11];
  const float* lnb = (const float*)d_in[12];
  float* ws = (float*)d_ws;
  float* out = (float*)d_out;
  if (ws_size < (size_t)WS_FLOATS * 4) return;

  hipMemsetAsync(ws + OFF_CNT, 0, 50000 * 4, stream);
  hipMemsetAsync(ws + OFF_DENOM, 0, 64, stream);

  k0_prep<<<K2DIM + 1, 128, 0, stream>>>(Wm, bm, Wa, ba, Wo, gm, ws);
  k0b_nodeproj<<<12500, 256, 0, stream>>>(x, Wa, ws);
  k_count<<<2048, 256, 0, stream>>>(ei, ws);
  k_scan<<<1, 1024, 0, stream>>>(ws);
  k_pos<<<2048, 256, 0, stream>>>(ei, ws);
  k1c<<<4096, 256, 0, stream>>>(ei, ef, td, ws);
  k4a_agg<<<2560, 256, 0, stream>>>(ws);
  k4b_mlp<<<(NPAD / 64), 256, 0, stream>>>(bo, lng, lnb, ws, out);
}

// Round 17
// 406.149 us; speedup vs baseline: 1.1246x; 1.0483x over previous
//
#include <hip/hip_runtime.h>
#include <math.h>

#define N_NODES 50000
#define N_EDGES 800000
#define ND 128
#define ED 64
#define TD 16
#define OD 128
#define NH 4
#define INDIM 208   // ND+ED+TD
#define K2DIM 336   // INDIM + ND
#define KPAD 352    // K2DIM padded to 11*32
#define WTPITCH 360 // Wt row pitch in bf16 (bank-spread)
#define NPAD 50048  // nodes padded to 64

// workspace layout (float offsets). einfoC/efc are CSR-ORDERED (scattered by k1c).
// einfo layout: pk.x = s | dt16<<16 ; pk.y = bf16(ev0)|bf16(ev1)<<16 ;
//               pk.z = bf16(ev2)|bf16(ev3)<<16 ; pk.w = 0
#define OFF_A      0ll           // 50048*352 ushort = 8,808,448 floats
#define OFF_EINFO  8808448ll     // 800000 uint4, CSR order
#define OFF_RANK   12008448ll    // 800000 ints (k_count: rank; k_pos overwrites with pos)
#define OFF_DENOM  12808448ll    // 16
#define OFF_SPG    12808464ll    // 16
#define OFF_WFUSE  12808480ll    // 832
#define OFF_BFUSE  12809312ll    // 16
#define OFF_BMO    12809328ll    // 128
#define OFF_XS4    12809456ll    // 200000
#define OFF_XD4    13009456ll    // 200000
#define OFF_CNT    13209456ll    // 50000 ints
#define OFF_START  13259456ll    // 50016 ints
#define OFF_SW     13309472ll    // 50048 floats
#define OFF_WT     13359520ll    // 128*360 ushort = 23040 floats
#define OFF_EFC    13382560ll    // 800000*64 ushort, CSR order = 25,600,000 floats
#define OFF_XBF    38982560ll    // 50000*128 ushort = 3,200,000 floats
#define WS_FLOATS  42182560ll

typedef __attribute__((ext_vector_type(8))) short short8v;
typedef __attribute__((ext_vector_type(4))) float f32x4;

__device__ inline unsigned short f2bf(float f) {
  unsigned u = __float_as_uint(f);
  unsigned r = (u + 0x7fffu + ((u >> 16) & 1u)) >> 16;
  return (unsigned short)r;
}
__device__ inline float bf2f(unsigned us) {
  return __uint_as_float(us << 16);
}

// ---------------- K0: fold weights + build bf16 Wt ----------------
__global__ void k0_prep(const float* __restrict__ Wm, const float* __restrict__ bm,
                        const float* __restrict__ Wa, const float* __restrict__ ba,
                        const float* __restrict__ Wo, const float* __restrict__ gammas,
                        float* __restrict__ ws) {
  int b = blockIdx.x, j = threadIdx.x;
  unsigned short* Wt = (unsigned short*)(ws + OFF_WT);
  if (b < INDIM) {
    float acc = 0.f;
    for (int m = 0; m < OD; ++m) acc += Wm[b * OD + m] * Wo[m * OD + j];
    Wt[j * WTPITCH + b] = f2bf(acc);
    if (j < NH) {
      float a = 0.f;
      for (int m = 0; m < OD; ++m) a += Wm[b * OD + m] * Wa[m * NH + j];
      ws[OFF_WFUSE + (long)b * NH + j] = a;
    }
  } else if (b < K2DIM) {
    Wt[j * WTPITCH + b] = f2bf(Wo[(OD + b - INDIM) * OD + j]);
  } else {
    if (j < TD) ws[OFF_SPG + j] = log1pf(expf(gammas[j]));
    if (j < NH) {
      float a = ba[j];
      for (int m = 0; m < OD; ++m) a += bm[m] * Wa[m * NH + j];
      ws[OFF_BFUSE + j] = a;
    }
    float a2 = 0.f;
    for (int m = 0; m < OD; ++m) a2 += bm[m] * Wo[m * OD + j];
    ws[OFF_BMO + j] = a2;
    for (int p = K2DIM; p < KPAD; ++p) Wt[j * WTPITCH + p] = 0;
  }
}

// ---------------- K0b: per-node 4-dim projections + x -> bf16 copy ----------------
__global__ __launch_bounds__(256) void k0b_nodeproj(
    const float* __restrict__ x, const float* __restrict__ Wa,
    float* __restrict__ ws) {
  __shared__ float wf[ND * NH];
  __shared__ float wab[ND * NH];
  int tid = threadIdx.x;
  for (int i = tid; i < ND * NH; i += 256) { wf[i] = ws[OFF_WFUSE + i]; wab[i] = Wa[ND * NH + i]; }
  __syncthreads();
  int lane = tid & 63, wv = tid >> 6;
  long n = (long)blockIdx.x * 4 + wv;
  if (n >= N_NODES) return;
  float v0 = x[n * ND + lane], v1 = x[n * ND + 64 + lane];
  unsigned short* xbf = (unsigned short*)(ws + OFF_XBF);
  xbf[n * ND + lane] = f2bf(v0);
  xbf[n * ND + 64 + lane] = f2bf(v1);
  float s0, s1, s2, s3, d0, d1, d2, d3;
  s0 = v0 * wf[lane * 4 + 0] + v1 * wf[(64 + lane) * 4 + 0];
  s1 = v0 * wf[lane * 4 + 1] + v1 * wf[(64 + lane) * 4 + 1];
  s2 = v0 * wf[lane * 4 + 2] + v1 * wf[(64 + lane) * 4 + 2];
  s3 = v0 * wf[lane * 4 + 3] + v1 * wf[(64 + lane) * 4 + 3];
  d0 = v0 * wab[lane * 4 + 0] + v1 * wab[(64 + lane) * 4 + 0];
  d1 = v0 * wab[lane * 4 + 1] + v1 * wab[(64 + lane) * 4 + 1];
  d2 = v0 * wab[lane * 4 + 2] + v1 * wab[(64 + lane) * 4 + 2];
  d3 = v0 * wab[lane * 4 + 3] + v1 * wab[(64 + lane) * 4 + 3];
  for (int off = 32; off; off >>= 1) {
    s0 += __shfl_xor(s0, off); s1 += __shfl_xor(s1, off);
    s2 += __shfl_xor(s2, off); s3 += __shfl_xor(s3, off);
    d0 += __shfl_xor(d0, off); d1 += __shfl_xor(d1, off);
    d2 += __shfl_xor(d2, off); d3 += __shfl_xor(d3, off);
  }
  if (lane == 0) {
    reinterpret_cast<float4*>(ws + OFF_XS4)[n] = make_float4(s0, s1, s2, s3);
    reinterpret_cast<float4*>(ws + OFF_XD4)[n] = make_float4(d0, d1, d2, d3);
  }
}

// ---------------- K_count: dst histogram + per-edge rank (atomic return value) ----------------
__global__ __launch_bounds__(256) void k_count(const int* __restrict__ ei,
                                               float* __restrict__ ws) {
  int* cnt = reinterpret_cast<int*>(ws + OFF_CNT);
  int* rank = reinterpret_cast<int*>(ws + OFF_RANK);
  for (long e = (long)blockIdx.x * 256 + threadIdx.x; e < N_EDGES;
       e += (long)gridDim.x * 256)
    rank[e] = atomicAdd(&cnt[ei[N_EDGES + e]], 1);
}

// ---------------- K_scan: exclusive scan (1024 threads) ----------------
__global__ __launch_bounds__(1024) void k_scan(float* __restrict__ ws) {
  const int* cnt = reinterpret_cast<const int*>(ws + OFF_CNT);
  int* startp = reinterpret_cast<int*>(ws + OFF_START);
  __shared__ int wsum[16];
  int tid = threadIdx.x;
  int lo = tid * 49, hi = min(lo + 49, N_NODES);
  int s = 0;
  for (int i = lo; i < hi; ++i) s += cnt[i];
  int lane = tid & 63, wv = tid >> 6;
  int sc = s;
  for (int off = 1; off < 64; off <<= 1) {
    int t = __shfl_up(sc, off);
    if (lane >= off) sc += t;
  }
  if (lane == 63) wsum[wv] = sc;
  __syncthreads();
  if (tid == 0) {
    int run = 0;
    for (int i = 0; i < 16; ++i) { int t = wsum[i]; wsum[i] = run; run += t; }
  }
  __syncthreads();
  int run = wsum[wv] + sc - s;   // exclusive prefix for this thread
  for (int i = lo; i < hi; ++i) { startp[i] = run; run += cnt[i]; }
  if (tid == 1023) startp[N_NODES] = run;
}

// ---------------- K_pos: pos[e] = start[dst[e]] + rank[e] (overwrites rank) ----------------
__global__ __launch_bounds__(256) void k_pos(const int* __restrict__ ei,
                                             float* __restrict__ ws) {
  const int* startp = reinterpret_cast<const int*>(ws + OFF_START);
  int* pr = reinterpret_cast<int*>(ws + OFF_RANK);
  for (long e = (long)blockIdx.x * 256 + threadIdx.x; e < N_EDGES;
       e += (long)gridDim.x * 256) {
    int d = ei[N_EDGES + e];
    pr[e] = startp[d] + pr[e];
  }
}

// ---------------- K1c: stream ef; scatter bf16 ef-row + einfo record into CSR slot ----------------
// 16 lanes per edge (proven best form). pos precomputed by k_pos -- NO atomics,
// stores are fire-and-forget. k4a then reads everything per-node CONTIGUOUSLY.
__global__ __launch_bounds__(256) void k1c(
    const int* __restrict__ ei, const float* __restrict__ ef,
    const float* __restrict__ td, float* __restrict__ ws) {
  __shared__ float wef[ED * NH];
  __shared__ float wte[TD * NH];
  __shared__ float bf[NH];
  __shared__ float spg[TD];
  __shared__ float part[NH];
  int tid = threadIdx.x;
  for (int i = tid; i < ED * NH; i += 256) wef[i] = ws[OFF_WFUSE + ND * NH + i];
  if (tid < TD * NH) wte[tid] = ws[OFF_WFUSE + (ND + ED) * NH + tid];
  if (tid < NH) { bf[tid] = ws[OFF_BFUSE + tid]; part[tid] = 0.f; }
  if (tid < TD) spg[tid] = ws[OFF_SPG + tid];
  __syncthreads();

  int lane = tid & 63;
  int q = lane >> 4, r = lane & 15, h = r & 3;
  long wid = ((long)blockIdx.x * 256 + tid) >> 6;
  long stride = (long)gridDim.x * 16;
  const float4* ef4 = reinterpret_cast<const float4*>(ef);
  const float* xsf = ws + OFF_XS4;
  const float* xdf = ws + OFF_XD4;
  const int* posArr = reinterpret_cast<const int*>(ws + OFF_RANK);
  uint2* efc2 = reinterpret_cast<uint2*>(ws + OFF_EFC);
  uint4* einfoC = reinterpret_cast<uint4*>(ws + OFF_EINFO);

  float wr[16];
#pragma unroll
  for (int i = 0; i < 16; ++i) wr[i] = wef[16 * r + i];
  float spg_r = spg[r];
  float wt0 = wte[r * 4 + 0], wt1 = wte[r * 4 + 1];
  float wt2 = wte[r * 4 + 2], wt3 = wte[r * 4 + 3];
  float bfh = bf[h];
  float p = 0.f;
  int base16 = lane & 48;

  for (long e = wid * 4 + q; e < N_EDGES; e += stride) {
    int s = ei[e];
    int d = ei[N_EDGES + e];
    float dt = fmaxf(td[e], 0.f);
    int pos = posArr[e];
    float4 efv = ef4[e * 16 + r];
    float ls = xsf[4l * s + h];
    float ld = xdf[4l * d + h];
    float te = __expf(-spg_r * dt);
    // bf16 ef row scattered to CSR slot (16 lanes -> one contiguous 128B line)
    uint2 eb;
    eb.x = (unsigned)f2bf(efv.x) | ((unsigned)f2bf(efv.y) << 16);
    eb.y = (unsigned)f2bf(efv.z) | ((unsigned)f2bf(efv.w) << 16);
    efc2[(long)pos * 16 + r] = eb;
    float a0 = efv.x * wr[0] + efv.y * wr[4] + efv.z * wr[8]  + efv.w * wr[12] + te * wt0;
    float a1 = efv.x * wr[1] + efv.y * wr[5] + efv.z * wr[9]  + efv.w * wr[13] + te * wt1;
    float a2 = efv.x * wr[2] + efv.y * wr[6] + efv.z * wr[10] + efv.w * wr[14] + te * wt2;
    float a3 = efv.x * wr[3] + efv.y * wr[7] + efv.z * wr[11] + efv.w * wr[15] + te * wt3;
    a0 += __shfl_xor(a0, 1); a1 += __shfl_xor(a1, 1);
    a2 += __shfl_xor(a2, 1); a3 += __shfl_xor(a3, 1);
    a0 += __shfl_xor(a0, 2); a1 += __shfl_xor(a1, 2);
    a2 += __shfl_xor(a2, 2); a3 += __shfl_xor(a3, 2);
    float v = a0;
    v = (h == 1) ? a1 : v;
    v = (h == 2) ? a2 : v;
    v = (h == 3) ? a3 : v;
    v += __shfl_xor(v, 4);
    v += __shfl_xor(v, 8);
    float ev = __expf(v + ls + ld + bfh);
    if (r < 4) p += ev;
    float e0 = __shfl(ev, base16 + 0), e1 = __shfl(ev, base16 + 1);
    float e2 = __shfl(ev, base16 + 2), e3 = __shfl(ev, base16 + 3);
    if (r == 0) {
      unsigned dt16 = (unsigned)(dt * 65535.f + 0.5f);
      if (dt16 > 65535u) dt16 = 65535u;
      uint4 pk;
      pk.x = (unsigned)s | (dt16 << 16);
      pk.y = (unsigned)f2bf(e0) | ((unsigned)f2bf(e1) << 16);
      pk.z = (unsigned)f2bf(e2) | ((unsigned)f2bf(e3) << 16);
      pk.w = 0u;
      einfoC[pos] = pk;
    }
  }
  p += __shfl_xor(p, 16);
  p += __shfl_xor(p, 32);
  if (lane < 4) atomicAdd(&part[lane], p);
  __syncthreads();
  if (tid < NH) atomicAdd(&ws[OFF_DENOM + tid], part[tid]);
}

// ---------------- K4a: CSR aggregation — STREAMING einfoC/efc, xbf gathers only ----------------
__global__ __launch_bounds__(256) void k4a_agg(float* __restrict__ ws) {
  __shared__ float spg_s[TD];
  __shared__ float invs[NH];
  int tid = threadIdx.x;
  if (tid < TD) spg_s[tid] = ws[OFF_SPG + tid];
  if (tid < NH) invs[tid] = 0.25f / ws[OFF_DENOM + tid];
  __syncthreads();
  int lane = tid & 63;
  long wid = (long)blockIdx.x * 4 + (tid >> 6);
  long nw = (long)gridDim.x * 4;
  const int* start = reinterpret_cast<const int*>(ws + OFF_START);
  const uint4* einfoC = reinterpret_cast<const uint4*>(ws + OFF_EINFO);
  unsigned short* A = (unsigned short*)(ws + OFF_A);
  const unsigned short* xbf = (const unsigned short*)(ws + OFF_XBF);
  const unsigned short* efc = (const unsigned short*)(ws + OFF_EFC);
  float spg_l = spg_s[lane & 15];
  float inv0 = invs[0], inv1 = invs[1], inv2 = invs[2], inv3 = invs[3];

  for (long n = wid; n < N_NODES; n += nw) {
    int i0 = start[n], i1 = start[n + 1];
    float a0 = 0.f, a1 = 0.f, a2 = 0.f, a3 = 0.f, asw = 0.f;
    for (int base = i0; base < i1; base += 64) {
      int m = min(64, i1 - base);
      uint4 pk = make_uint4(0u, 0u, 0u, 0u);
      if (lane < m) pk = einfoC[base + lane];   // coalesced
      int j = 0;
      for (; j + 4 <= m; j += 4) {
        unsigned xu[4], zu[4], wu[4];
#pragma unroll
        for (int u = 0; u < 4; ++u) {
          xu[u] = (unsigned)__shfl((int)pk.x, j + u);
          zu[u] = (unsigned)__shfl((int)pk.y, j + u);
          wu[u] = (unsigned)__shfl((int)pk.z, j + u);
        }
        unsigned xa[4], xb[4], ec[4];
#pragma unroll
        for (int u = 0; u < 4; ++u) {
          int s = (int)(xu[u] & 0xffffu);
          xa[u] = xbf[(long)s * ND + lane];
          xb[u] = xbf[(long)s * ND + 64 + lane];
          ec[u] = efc[(long)(base + j + u) * ED + lane];   // streaming
        }
#pragma unroll
        for (int u = 0; u < 4; ++u) {
          float w = bf2f(zu[u] & 0xffffu) * inv0 + bf2f(zu[u] >> 16) * inv1 +
                    bf2f(wu[u] & 0xffffu) * inv2 + bf2f(wu[u] >> 16) * inv3;
          float dt = (float)(xu[u] >> 16) * (1.f / 65535.f);
          a0 += w * bf2f(xa[u]);
          a1 += w * bf2f(xb[u]);
          a2 += w * bf2f(ec[u]);
          a3 += w * __expf(-spg_l * dt);
          asw += w;
        }
      }
      for (; j < m; ++j) {
        unsigned xu = (unsigned)__shfl((int)pk.x, j);
        unsigned zu = (unsigned)__shfl((int)pk.y, j);
        unsigned wu = (unsigned)__shfl((int)pk.z, j);
        int s = (int)(xu & 0xffffu);
        float w = bf2f(zu & 0xffffu) * inv0 + bf2f(zu >> 16) * inv1 +
                  bf2f(wu & 0xffffu) * inv2 + bf2f(wu >> 16) * inv3;
        float dt = (float)(xu >> 16) * (1.f / 65535.f);
        a0 += w * bf2f(xbf[(long)s * ND + lane]);
        a1 += w * bf2f(xbf[(long)s * ND + 64 + lane]);
        a2 += w * bf2f(efc[(long)(base + j) * ED + lane]);
        a3 += w * __expf(-spg_l * dt);
        asw += w;
      }
    }
    unsigned short* Ar = A + n * KPAD;
    Ar[lane] = f2bf(a0);
    Ar[64 + lane] = f2bf(a1);
    Ar[128 + lane] = f2bf(a2);
    if (lane < TD) Ar[192 + lane] = f2bf(a3);
    Ar[INDIM + lane] = xbf[n * ND + lane];
    Ar[INDIM + 64 + lane] = xbf[n * ND + 64 + lane];
    if (lane < 16) Ar[K2DIM + lane] = 0;
    if (lane == 0) ws[OFF_SW + n] = asw;
  }
}

// ---------------- K4b: MFMA bf16 GEMM (NPAD x KPAD @ KPAD x 128) + GELU + LN ----------------
__global__ __launch_bounds__(256) void k4b_mlp(
    const float* __restrict__ bo, const float* __restrict__ lng,
    const float* __restrict__ lnb, const float* __restrict__ ws,
    float* __restrict__ out) {
  __shared__ unsigned short wt[128 * WTPITCH];  // 90 KB, transposed W, bank-spread pitch
  __shared__ float tbl[512];                    // bo | bmj | lng | lnb
  int tid = threadIdx.x;
  {
    const unsigned* wg = (const unsigned*)(ws + OFF_WT);
    unsigned* wl = (unsigned*)wt;
    for (int i = tid; i < 128 * WTPITCH / 2; i += 256) wl[i] = wg[i];
    if (tid < 128) {
      tbl[tid] = bo[tid];
      tbl[128 + tid] = ws[OFF_BMO + tid];
      tbl[256 + tid] = lng[tid];
      tbl[384 + tid] = lnb[tid];
    }
  }
  __syncthreads();

  int lane = tid & 63, wv = tid >> 6;
  int c0 = lane & 15, grp = lane >> 4;
  long n0 = (long)blockIdx.x * 64 + (long)wv * 16;
  const unsigned short* A = (const unsigned short*)(ws + OFF_A);
  const unsigned short* Arow = A + (n0 + c0) * KPAD;

  f32x4 acc[8];
#pragma unroll
  for (int t = 0; t < 8; ++t) acc[t] = (f32x4){0.f, 0.f, 0.f, 0.f};

#pragma unroll
  for (int kt = 0; kt < 11; ++kt) {
    short8v afrag = *reinterpret_cast<const short8v*>(Arow + kt * 32 + grp * 8);
#pragma unroll
    for (int t = 0; t < 8; ++t) {
      short8v bfrag = *reinterpret_cast<const short8v*>(&wt[(t * 16 + c0) * WTPITCH + kt * 32 + grp * 8]);
      acc[t] = __builtin_amdgcn_mfma_f32_16x16x32_bf16(afrag, bfrag, acc[t], 0, 0, 0);
    }
  }

  const float* swp = ws + OFF_SW;
  float res[4][8];
#pragma unroll
  for (int r = 0; r < 4; ++r) {
    long row = n0 + grp * 4 + r;
    float sw = swp[row];
    float s = 0.f, s2 = 0.f;
#pragma unroll
    for (int t = 0; t < 8; ++t) {
      int col = c0 + 16 * t;
      float a = acc[t][r] + tbl[col] + sw * tbl[128 + col];
      float h = 0.5f * a * (1.f + erff(a * 0.70710678118654752f));
      res[r][t] = h;
      s += h; s2 += h * h;
    }
    s += __shfl_xor(s, 1);  s2 += __shfl_xor(s2, 1);
    s += __shfl_xor(s, 2);  s2 += __shfl_xor(s2, 2);
    s += __shfl_xor(s, 4);  s2 += __shfl_xor(s2, 4);
    s += __shfl_xor(s, 8);  s2 += __shfl_xor(s2, 8);
    float mu = s * (1.f / 128.f);
    float var = s2 * (1.f / 128.f) - mu * mu;
    float rstd = rsqrtf(var + 1e-5f);
    if (row < N_NODES) {
      float* op = out + row * OD;
#pragma unroll
      for (int t = 0; t < 8; ++t) {
        int col = c0 + 16 * t;
        op[col] = (res[r][t] - mu) * rstd * tbl[256 + col] + tbl[384 + col];
      }
    }
  }
}

extern "C" void kernel_launch(void* const* d_in, const int* in_sizes, int n_in,
                              void* d_out, int out_size, void* d_ws, size_t ws_size,
                              hipStream_t stream) {
  const float* x   = (const float*)d_in[0];
  const int*   ei  = (const int*)d_in[1];
  const float* ef  = (const float*)d_in[2];
  const float* td  = (const float*)d_in[3];
  const float* gm  = (const float*)d_in[4];
  const float* Wm  = (const float*)d_in[5];
  const float* bm  = (const float*)d_in[6];
  const float* Wa  = (const float*)d_in[7];
  const float* ba  = (const float*)d_in[8];
  const float* Wo  = (const float*)d_in[9];
  const float* bo  = (const float*)d_in[10];
  const float* lng = (const float*)d_in[11];
  const float* lnb = (const float*)d_in[12];
  float* ws = (float*)d_ws;
  float* out = (float*)d_out;
  if (ws_size < (size_t)WS_FLOATS * 4) return;

  hipMemsetAsync(ws + OFF_CNT, 0, 50000 * 4, stream);
  hipMemsetAsync(ws + OFF_DENOM, 0, 64, stream);

  k0_prep<<<K2DIM + 1, 128, 0, stream>>>(Wm, bm, Wa, ba, Wo, gm, ws);
  k0b_nodeproj<<<12500, 256, 0, stream>>>(x, Wa, ws);
  k_count<<<2048, 256, 0, stream>>>(ei, ws);
  k_scan<<<1, 1024, 0, stream>>>(ws);
  k_pos<<<2048, 256, 0, stream>>>(ei, ws);
  k1c<<<3072, 256, 0, stream>>>(ei, ef, td, ws);
  k4a_agg<<<2048, 256, 0, stream>>>(ws);
  k4b_mlp<<<(NPAD / 64), 256, 0, stream>>>(bo, lng, lnb, ws, out);
}